// Round 9
// baseline (53.090 us; speedup 1.0000x reference)
//
#include <hip/hip_runtime.h>

// CLF_K_QP_Net — bf16 MFMA, R9. B=65536, N=16, H=128, NC=2.
// R8→R9: eliminate per-wave act LDS (t1/s2/c) — keep activations as packed
// bf16 D-frag pairs in registers, regroup D-frag -> B-frag via the
// R6-verified 32-bpermute pattern (same as ksecond). LDS drops 128KB -> 64KB
// (V2s/V2Ts only) -> 2 blocks/CU -> 4 waves/SIMD (was 2). launch_bounds(512,4)
// caps VGPR at 128 to hold that occupancy; live set est. ~110.
// R8 counters: VALUBusy 27%, Mfma 5%, occ 19% -> latency-bound; compute floor
// ~2.75x below measured. This round trades DS round-trips for TLP.

typedef __attribute__((ext_vector_type(8))) short bf8_t;   // MFMA A/B frag
typedef __attribute__((ext_vector_type(4))) float f4_t;    // MFMA C/D frag

#define MFMA16(a, b, c) __builtin_amdgcn_mfma_f32_16x16x32_bf16((a), (b), (c), 0, 0, 0)

__device__ __forceinline__ float fast_tanh(float v) {
    float e = __builtin_amdgcn_exp2f(v * 2.885390081777927f);   // e^{2v}
    return 1.0f - 2.0f * __builtin_amdgcn_rcpf(e + 1.0f);       // inf-safe
}
__device__ __forceinline__ unsigned short bf16_of(float f) {
    union { float f; unsigned u; } v; v.f = f;
    return (unsigned short)((v.u + 0x8000u) >> 16);
}
__device__ __forceinline__ unsigned pk2(float a, float b) {
    union { float f; unsigned u; } va, vb; va.f = a; vb.f = b;
    return ((va.u + 0x8000u) >> 16) | ((vb.u + 0x8000u) & 0xFFFF0000u);
}
__device__ __forceinline__ float unbf(unsigned s) {           // low 16 bits
    union { unsigned u; float f; } v; v.u = s << 16; return v.f;
}
__device__ __forceinline__ float unbf_hi(unsigned s) {        // high 16 bits
    union { unsigned u; float f; } v; v.u = s & 0xFFFF0000u; return v.f;
}

// ws layout (bf16 element offsets):
// V1[128][16]:0  V1T[16][128]:2048  V2[128][128]:4096  V2T[128][128]:20480
// K1a[128][16]:36864  K2a[128][16]:38912  K1b[16][128]:40960  K2b[16][128]:43008
// A_dyn[16][16]:45056
__global__ void prep_weights(const float* __restrict__ V1_w,
                             const float* __restrict__ V2_w,
                             const float* __restrict__ K1a_w,
                             const float* __restrict__ K1b_w,
                             const float* __restrict__ K2a_w,
                             const float* __restrict__ K2b_w,
                             const float* __restrict__ A_dyn,
                             unsigned short* __restrict__ ws) {
    int i = blockIdx.x * 256 + threadIdx.x;
    if (i < 2048) {
        ws[i] = bf16_of(V1_w[i]);
        int k = i & 127;
        ws[2048 + i] = bf16_of(V1_w[k * 16 + (i >> 7)]);   // V1T[n][k]
        ws[36864 + i] = bf16_of(K1a_w[i]);
        ws[38912 + i] = bf16_of(K2a_w[i]);
        ws[40960 + i] = bf16_of(K1b_w[i]);
        ws[43008 + i] = bf16_of(K2b_w[i]);
    }
    if (i < 16384) {
        ws[4096 + i] = bf16_of(V2_w[i]);
        int k = i >> 7, h = i & 127;
        ws[20480 + i] = bf16_of(V2_w[h * 128 + k]);        // V2T[k][h]
    }
    if (i < 256) ws[45056 + i] = bf16_of(A_dyn[i]);
}

__device__ __forceinline__ bf8_t pack8(f4_t a, f4_t b) {
    union { bf8_t v; unsigned u[4]; } r;
    r.u[0] = pk2(a[0], a[1]); r.u[1] = pk2(a[2], a[3]);
    r.u[2] = pk2(b[0], b[1]); r.u[3] = pk2(b[2], b[3]);
    return r.v;
}

// D-frag pairs (rows t*16+4g+{0,1} in [0], +{2,3} in [1], col lr) -> B-frag
// chunks (lane holds k = c*32+g*8..+7 of col lr). Verified R6 (ksecond).
__device__ __forceinline__ void regroupB(const unsigned (&W)[8][2], bf8_t (&f)[4],
                                         int g, int lr) {
    const int srcA = (g & 1) * 32 + lr;
    const int srcB = srcA + 16;
    const bool hi = (g >> 1) != 0;
#pragma unroll
    for (int c = 0; c < 4; ++c) {
        unsigned a0 = __shfl(W[2 * c][0], srcA), b0 = __shfl(W[2 * c + 1][0], srcA);
        unsigned a1 = __shfl(W[2 * c][1], srcA), b1 = __shfl(W[2 * c + 1][1], srcA);
        unsigned a2 = __shfl(W[2 * c][0], srcB), b2 = __shfl(W[2 * c + 1][0], srcB);
        unsigned a3 = __shfl(W[2 * c][1], srcB), b3 = __shfl(W[2 * c + 1][1], srcB);
        union { bf8_t v; unsigned u[4]; } fr;
        fr.u[0] = hi ? b0 : a0;
        fr.u[1] = hi ? b1 : a1;
        fr.u[2] = hi ? b2 : a2;
        fr.u[3] = hi ? b3 : a3;
        f[c] = fr.v;
    }
}

// LDS: V2s + V2Ts only (64KB) -> 2 blocks/CU.
__global__ void __launch_bounds__(512, 4) clf_mfma_kernel(
    const float* __restrict__ x,
    const float* __restrict__ V1_b, const float* __restrict__ V2_b,
    const float* __restrict__ K1a_b, const float* __restrict__ K1b_b,
    const float* __restrict__ K2a_b, const float* __restrict__ K2b_b,
    const float* __restrict__ B_dyn, const float* __restrict__ x_goal,
    const float* __restrict__ u_eq,
    const unsigned short* __restrict__ ws, float* __restrict__ out, int B) {
    __shared__ unsigned short V2s[16384];
    __shared__ unsigned short V2Ts[16384];
    const int lane = threadIdx.x & 63;
    const int wv = threadIdx.x >> 6;       // 0..7
    const int lr = lane & 15;              // batch column
    const int g = lane >> 4;               // k-group / row-group
    const int bb = (blockIdx.x * 8 + wv) * 16 + lr;

    if (blockIdx.x == 0 && threadIdx.x == 0) out[2 * B] = 0.0f;  // relaxation

    // ---- stage V2, V2T into LDS with row-swizzle ----
#pragma unroll
    for (int q = 0; q < 4; ++q) {
        int e = (q * 512 + threadIdx.x) * 8;          // 8-elem chunk
        int r = e >> 7;
        int d = e ^ ((r & 7) << 3);
        *reinterpret_cast<uint4*>(&V2s[d])  = *reinterpret_cast<const uint4*>(ws + 4096 + e);
        *reinterpret_cast<uint4*>(&V2Ts[d]) = *reinterpret_cast<const uint4*>(ws + 20480 + e);
    }
    __syncthreads();

    const unsigned short* wsV1 = ws;
    const unsigned short* wsV1T = ws + 2048;
    const unsigned short* wsK1a = ws + 36864;
    const unsigned short* wsK2a = ws + 38912;
    const unsigned short* wsK1b = ws + 40960;
    const unsigned short* wsK2b = ws + 43008;
    const unsigned short* wsA = ws + 45056;

    const int swz = (lr & 7) << 3;
    auto ldW = [&](const unsigned short* Wt, int t, int c) -> bf8_t {
        int idx = ((t * 16 + lr) * 128 + c * 32 + g * 8) ^ swz;
        return *reinterpret_cast<const bf8_t*>(Wt + idx);
    };

    // ---- x fragment (B operand for K=16 GEMMs, zero-padded to 32) ----
    bf8_t xf = {0, 0, 0, 0, 0, 0, 0, 0};
    if (g < 2) {
        const float* xp = x + bb * 16 + g * 8;
        f4_t a = *reinterpret_cast<const f4_t*>(xp);
        f4_t b = *reinterpret_cast<const f4_t*>(xp + 4);
        xf = pack8(a, b);
    }

    // ---- first-layer tanh net -> register D-frag pairs ----
    auto actnet_reg = [&](const unsigned short* wsW, const float* bias, unsigned (&W)[8][2]) {
#pragma unroll
        for (int t = 0; t < 8; ++t) {
            bf8_t af = {0, 0, 0, 0, 0, 0, 0, 0};
            if (g < 2) af = *reinterpret_cast<const bf8_t*>(wsW + (t * 16 + lr) * 16 + g * 8);
            f4_t acc = {0.f, 0.f, 0.f, 0.f};
            acc = MFMA16(af, xf, acc);
            f4_t bs = *reinterpret_cast<const f4_t*>(bias + t * 16 + g * 4);
            float v0 = fast_tanh(acc[0] + bs[0]);
            float v1 = fast_tanh(acc[1] + bs[1]);
            float v2 = fast_tanh(acc[2] + bs[2]);
            float v3 = fast_tanh(acc[3] + bs[3]);
            W[t][0] = pk2(v0, v1);
            W[t][1] = pk2(v2, v3);
        }
    };
    // second layer over a global-memory A operand (K1b/K2b/V1T rows)
    auto kmul = [&](const unsigned short* wsKb, const bf8_t (&f)[4]) -> f4_t {
        f4_t k = {0.f, 0.f, 0.f, 0.f};
#pragma unroll
        for (int c = 0; c < 4; ++c) {
            const bf8_t* ar = reinterpret_cast<const bf8_t*>(wsKb + lr * 128 + c * 32 + g * 8);
            k = MFMA16(*ar, f[c], k);
        }
        return k;
    };

    // ---- t1 = tanh(V1 x + b): D-frag pairs + B-frag regroup ----
    unsigned T1[8][2];
    actnet_reg(wsV1, V1_b, T1);
    bf8_t t1f[4];
    regroupB(T1, t1f, g, lr);

    // ---- K nets (independent filler work) ----
    unsigned W1r[8][2];
    actnet_reg(wsK1a, K1a_b, W1r);
    bf8_t a1f[4];
    regroupB(W1r, a1f, g, lr);
    f4_t k1 = kmul(wsK1b, a1f);
    unsigned W2r[8][2];
    actnet_reg(wsK2a, K2a_b, W2r);
    bf8_t a2f[4];
    regroupB(W2r, a2f, g, lr);
    f4_t k2 = kmul(wsK2b, a2f);

    // ---- t2 pass: Z2^T = V2 . t1^T; V partials; s2 -> D-frag pairs ----
    unsigned S2[8][2];
    float vsum = 0.f;
#pragma unroll
    for (int t = 0; t < 8; ++t) {
        f4_t acc = {0.f, 0.f, 0.f, 0.f};
        acc = MFMA16(ldW(V2s, t, 0), t1f[0], acc);
        acc = MFMA16(ldW(V2s, t, 1), t1f[1], acc);
        acc = MFMA16(ldW(V2s, t, 2), t1f[2], acc);
        acc = MFMA16(ldW(V2s, t, 3), t1f[3], acc);
        f4_t bs = *reinterpret_cast<const f4_t*>(V2_b + t * 16 + g * 4);
        float s0, s1, s2v, s3;
        {
            float t2;
            t2 = fast_tanh(acc[0] + bs[0]); vsum = fmaf(t2, t2, vsum); s0 = t2 * (1.f - t2 * t2);
            t2 = fast_tanh(acc[1] + bs[1]); vsum = fmaf(t2, t2, vsum); s1 = t2 * (1.f - t2 * t2);
            t2 = fast_tanh(acc[2] + bs[2]); vsum = fmaf(t2, t2, vsum); s2v = t2 * (1.f - t2 * t2);
            t2 = fast_tanh(acc[3] + bs[3]); vsum = fmaf(t2, t2, vsum); s3 = t2 * (1.f - t2 * t2);
        }
        S2[t][0] = pk2(s0, s1);
        S2[t][1] = pk2(s2v, s3);
    }
    bf8_t s2f[4];
    regroupB(S2, s2f, g, lr);

    // ---- w^T = V2^T . s2^T ----
    f4_t wacc[8];
#pragma unroll
    for (int t = 0; t < 8; ++t) {
        f4_t acc = {0.f, 0.f, 0.f, 0.f};
        acc = MFMA16(ldW(V2Ts, t, 0), s2f[0], acc);
        acc = MFMA16(ldW(V2Ts, t, 1), s2f[1], acc);
        acc = MFMA16(ldW(V2Ts, t, 2), s2f[2], acc);
        acc = MFMA16(ldW(V2Ts, t, 3), s2f[3], acc);
        wacc[t] = acc;
    }

    // ---- c = w * (1 - t1^2) in D-layout (T1 values are lane-local) ----
    unsigned C[8][2];
#pragma unroll
    for (int t = 0; t < 8; ++t) {
        float t0v = unbf(T1[t][0]), t1v = unbf_hi(T1[t][0]);
        float t2v = unbf(T1[t][1]), t3v = unbf_hi(T1[t][1]);
        float c0 = wacc[t][0] * (1.f - t0v * t0v);
        float c1 = wacc[t][1] * (1.f - t1v * t1v);
        float c2 = wacc[t][2] * (1.f - t2v * t2v);
        float c3 = wacc[t][3] * (1.f - t3v * t3v);
        C[t][0] = pk2(c0, c1);
        C[t][1] = pk2(c2, c3);
    }
    bf8_t cf[4];
    regroupB(C, cf, g, lr);

    // ---- gV^T = V1^T . c^T ----
    f4_t gacc = kmul(wsV1T, cf);

    // ---- f^T = A_dyn . x^T ----
    bf8_t afA = {0, 0, 0, 0, 0, 0, 0, 0};
    if (g < 2) afA = *reinterpret_cast<const bf8_t*>(wsA + lr * 16 + g * 8);
    f4_t fz = {0.f, 0.f, 0.f, 0.f};
    f4_t fac = MFMA16(afA, xf, fz);

    // ---- epilogue ----
    f4_t xv = *reinterpret_cast<const f4_t*>(x + bb * 16 + g * 4);
    f4_t xg = *reinterpret_cast<const f4_t*>(x_goal + g * 4);
    f4_t k1b = *reinterpret_cast<const f4_t*>(K1b_b + g * 4);
    f4_t k2b = *reinterpret_cast<const f4_t*>(K2b_b + g * 4);
    f4_t bd0 = *reinterpret_cast<const f4_t*>(B_dyn + g * 8);
    f4_t bd1 = *reinterpret_cast<const f4_t*>(B_dyn + g * 8 + 4);
    float up0 = 0.f, up1 = 0.f, Lf = 0.f;
#pragma unroll
    for (int r = 0; r < 4; ++r) {
        float dx = xv[r] - xg[r];
        up0 = fmaf(k1[r] + k1b[r], dx, up0);
        up1 = fmaf(k2[r] + k2b[r], dx, up1);
        Lf = fmaf(gacc[r], fac[r], Lf);
    }
    float Lg0 = gacc[0] * bd0[0] + gacc[1] * bd0[2] + gacc[2] * bd1[0] + gacc[3] * bd1[2];
    float Lg1 = gacc[0] * bd0[1] + gacc[1] * bd0[3] + gacc[2] * bd1[1] + gacc[3] * bd1[3];
    up0 += __shfl_xor(up0, 16); up0 += __shfl_xor(up0, 32);
    up1 += __shfl_xor(up1, 16); up1 += __shfl_xor(up1, 32);
    Lf += __shfl_xor(Lf, 16); Lf += __shfl_xor(Lf, 32);
    Lg0 += __shfl_xor(Lg0, 16); Lg0 += __shfl_xor(Lg0, 32);
    Lg1 += __shfl_xor(Lg1, 16); Lg1 += __shfl_xor(Lg1, 32);
    vsum += __shfl_xor(vsum, 16); vsum += __shfl_xor(vsum, 32);

    float u0 = u_eq[0] - up0;
    float u1 = u_eq[1] - up1;
    float V = 0.5f * vsum;
    float G = fmaf(Lg0, u0, fmaf(Lg1, u1, V));
    float Vd = 0.5f * (fmaxf(Lf + G, 0.f) + fmaxf(fmaf(1.2f, Lf, G), 0.f));

    if (g == 0) {
        float2 uo; uo.x = u0; uo.y = u1;
        *reinterpret_cast<float2*>(out + 2 * bb) = uo;
    } else if (g == 1) {
        out[2 * B + 1 + bb] = V;
    } else if (g == 2) {
        out[3 * B + 1 + bb] = Vd;
    }
}

extern "C" void kernel_launch(void* const* d_in, const int* in_sizes, int n_in,
                              void* d_out, int out_size, void* d_ws, size_t ws_size,
                              hipStream_t stream) {
    const float* x = (const float*)d_in[0];
    const float* V1_w = (const float*)d_in[1];
    const float* V1_b = (const float*)d_in[2];
    const float* V2_w = (const float*)d_in[3];
    const float* V2_b = (const float*)d_in[4];
    const float* K1a_w = (const float*)d_in[5];
    const float* K1a_b = (const float*)d_in[6];
    const float* K1b_w = (const float*)d_in[7];
    const float* K1b_b = (const float*)d_in[8];
    const float* K2a_w = (const float*)d_in[9];
    const float* K2a_b = (const float*)d_in[10];
    const float* K2b_w = (const float*)d_in[11];
    const float* K2b_b = (const float*)d_in[12];
    const float* A_dyn = (const float*)d_in[13];
    const float* B_dyn = (const float*)d_in[14];
    const float* x_goal = (const float*)d_in[15];
    const float* u_eq = (const float*)d_in[16];
    float* out = (float*)d_out;
    unsigned short* ws = (unsigned short*)d_ws;

    const int B = in_sizes[0] / 16;   // 65536
    prep_weights<<<64, 256, 0, stream>>>(V1_w, V2_w, K1a_w, K1b_w, K2a_w, K2b_w, A_dyn, ws);
    clf_mfma_kernel<<<512, 512, 0, stream>>>(
        x, V1_b, V2_b, K1a_b, K1b_b, K2a_b, K2b_b,
        B_dyn, x_goal, u_eq, ws, out, B);
}

// Round 10
// 50.127 us; speedup vs baseline: 1.0591x; 1.0591x over previous
//
#include <hip/hip_runtime.h>

// CLF_K_QP_Net — bf16 MFMA, R10. B=65536, N=16, H=128, NC=2.
// R9 post-mortem: register-resident activations (T1+S2+C+wacc+frags ~140 regs)
// -> allocator drops to 64-VGPR tier + 95MB spill (same failure as R3/R7).
// R10: R8's LDS-roundtrip body (clean 88 VGPR) + R9's occupancy goal:
//  - ONE 4KB act buffer/wave, sequentially reused (a1->a1f->a2->a2f->t1->t1f->
//    s2->s2f->c->cf); t1 also kept as D-frag regs T1[8][2] for the c-step,
//    which is what frees the second buffer. Same-wave DS ordering = no barriers.
//  - 16-wave blocks (1024 thr), grid 256 = 1 block/CU: LDS 64K(V2s+V2Ts,
//    now amortized over 16 waves) + 64K act = 128KB -> 4 waves/SIMD (2x R8).
//  - plain __launch_bounds__(1024) (only variant that allocated cleanly, R8).
//  - split MFMA accumulator chains (acc_a/acc_b) in t2/w passes.

typedef __attribute__((ext_vector_type(8))) short bf8_t;   // MFMA A/B frag
typedef __attribute__((ext_vector_type(4))) float f4_t;    // MFMA C/D frag

#define MFMA16(a, b, c) __builtin_amdgcn_mfma_f32_16x16x32_bf16((a), (b), (c), 0, 0, 0)

__device__ __forceinline__ float fast_tanh(float v) {
    float e = __builtin_amdgcn_exp2f(v * 2.885390081777927f);   // e^{2v}
    return 1.0f - 2.0f * __builtin_amdgcn_rcpf(e + 1.0f);       // inf-safe
}
__device__ __forceinline__ unsigned short bf16_of(float f) {
    union { float f; unsigned u; } v; v.f = f;
    return (unsigned short)((v.u + 0x8000u) >> 16);
}
__device__ __forceinline__ unsigned pk2(float a, float b) {
    union { float f; unsigned u; } va, vb; va.f = a; vb.f = b;
    return ((va.u + 0x8000u) >> 16) | ((vb.u + 0x8000u) & 0xFFFF0000u);
}
__device__ __forceinline__ float unbf(unsigned s) {           // low 16 bits
    union { unsigned u; float f; } v; v.u = s << 16; return v.f;
}
__device__ __forceinline__ float unbf_hi(unsigned s) {        // high 16 bits
    union { unsigned u; float f; } v; v.u = s & 0xFFFF0000u; return v.f;
}

// ws layout (bf16 element offsets):
// V1[128][16]:0  V1T[16][128]:2048  V2[128][128]:4096  V2T[128][128]:20480
// K1a[128][16]:36864  K2a[128][16]:38912  K1b[16][128]:40960  K2b[16][128]:43008
// A_dyn[16][16]:45056
__global__ void prep_weights(const float* __restrict__ V1_w,
                             const float* __restrict__ V2_w,
                             const float* __restrict__ K1a_w,
                             const float* __restrict__ K1b_w,
                             const float* __restrict__ K2a_w,
                             const float* __restrict__ K2b_w,
                             const float* __restrict__ A_dyn,
                             unsigned short* __restrict__ ws) {
    int i = blockIdx.x * 256 + threadIdx.x;
    if (i < 2048) {
        ws[i] = bf16_of(V1_w[i]);
        int k = i & 127;
        ws[2048 + i] = bf16_of(V1_w[k * 16 + (i >> 7)]);   // V1T[n][k]
        ws[36864 + i] = bf16_of(K1a_w[i]);
        ws[38912 + i] = bf16_of(K2a_w[i]);
        ws[40960 + i] = bf16_of(K1b_w[i]);
        ws[43008 + i] = bf16_of(K2b_w[i]);
    }
    if (i < 16384) {
        ws[4096 + i] = bf16_of(V2_w[i]);
        int k = i >> 7, h = i & 127;
        ws[20480 + i] = bf16_of(V2_w[h * 128 + k]);        // V2T[k][h]
    }
    if (i < 256) ws[45056 + i] = bf16_of(A_dyn[i]);
}

__device__ __forceinline__ bf8_t pack8(f4_t a, f4_t b) {
    union { bf8_t v; unsigned u[4]; } r;
    r.u[0] = pk2(a[0], a[1]); r.u[1] = pk2(a[2], a[3]);
    r.u[2] = pk2(b[0], b[1]); r.u[3] = pk2(b[2], b[3]);
    return r.v;
}

// LDS (shorts): V2s[16384] | V2Ts[16384] | 16 waves x act[2048]  = 128 KB
__global__ void __launch_bounds__(1024) clf_mfma_kernel(
    const float* __restrict__ x,
    const float* __restrict__ V1_b, const float* __restrict__ V2_b,
    const float* __restrict__ K1a_b, const float* __restrict__ K1b_b,
    const float* __restrict__ K2a_b, const float* __restrict__ K2b_b,
    const float* __restrict__ B_dyn, const float* __restrict__ x_goal,
    const float* __restrict__ u_eq,
    const unsigned short* __restrict__ ws, float* __restrict__ out, int B) {
    extern __shared__ unsigned short sm[];
    unsigned short* V2s = sm;
    unsigned short* V2Ts = sm + 16384;
    const int lane = threadIdx.x & 63;
    const int wv = threadIdx.x >> 6;       // 0..15
    const int lr = lane & 15;              // batch column
    const int g = lane >> 4;               // k-group / row-group
    const int bb = (blockIdx.x * 16 + wv) * 16 + lr;
    unsigned short* buf = sm + 32768 + wv * 2048;   // single 4KB act buffer

    if (blockIdx.x == 0 && threadIdx.x == 0) out[2 * B] = 0.0f;  // relaxation

    // ---- stage V2, V2T into LDS with row-swizzle ----
#pragma unroll
    for (int q = 0; q < 2; ++q) {
        int e = (q * 1024 + threadIdx.x) * 8;         // 8-elem chunk
        int r = e >> 7;
        int d = e ^ ((r & 7) << 3);
        *reinterpret_cast<uint4*>(&V2s[d])  = *reinterpret_cast<const uint4*>(ws + 4096 + e);
        *reinterpret_cast<uint4*>(&V2Ts[d]) = *reinterpret_cast<const uint4*>(ws + 20480 + e);
    }
    __syncthreads();

    const unsigned short* wsV1 = ws;
    const unsigned short* wsV1T = ws + 2048;
    const unsigned short* wsK1a = ws + 36864;
    const unsigned short* wsK2a = ws + 38912;
    const unsigned short* wsK1b = ws + 40960;
    const unsigned short* wsK2b = ws + 43008;
    const unsigned short* wsA = ws + 45056;

    const int swz = (lr & 7) << 3;
    auto stA = [&](int h0, unsigned lo, unsigned hi) {
        int idx = (lr * 128 + h0) ^ swz;
        uint2 v; v.x = lo; v.y = hi;
        *reinterpret_cast<uint2*>(buf + idx) = v;
    };
    auto ld8 = [&](int h0) -> bf8_t {
        int idx = (lr * 128 + h0) ^ swz;
        return *reinterpret_cast<const bf8_t*>(buf + idx);
    };
    auto ldW = [&](const unsigned short* Wt, int t, int c) -> bf8_t {
        int idx = ((t * 16 + lr) * 128 + c * 32 + g * 8) ^ swz;
        return *reinterpret_cast<const bf8_t*>(Wt + idx);
    };

    // ---- x fragment (B operand for K=16 GEMMs, zero-padded to 32) ----
    bf8_t xf = {0, 0, 0, 0, 0, 0, 0, 0};
    if (g < 2) {
        const float* xp = x + bb * 16 + g * 8;
        f4_t a = *reinterpret_cast<const f4_t*>(xp);
        f4_t b = *reinterpret_cast<const f4_t*>(xp + 4);
        xf = pack8(a, b);
    }

    // ---- first-layer tanh net -> act buf (optionally keep D-frag pairs) ----
    auto actnet = [&](const unsigned short* wsW, const float* bias, unsigned* keep) {
#pragma unroll
        for (int t = 0; t < 8; ++t) {
            bf8_t af = {0, 0, 0, 0, 0, 0, 0, 0};
            if (g < 2) af = *reinterpret_cast<const bf8_t*>(wsW + (t * 16 + lr) * 16 + g * 8);
            f4_t acc = {0.f, 0.f, 0.f, 0.f};
            acc = MFMA16(af, xf, acc);
            f4_t bs = *reinterpret_cast<const f4_t*>(bias + t * 16 + g * 4);
            float v0 = fast_tanh(acc[0] + bs[0]);
            float v1 = fast_tanh(acc[1] + bs[1]);
            float v2 = fast_tanh(acc[2] + bs[2]);
            float v3 = fast_tanh(acc[3] + bs[3]);
            unsigned lo = pk2(v0, v1), hi = pk2(v2, v3);
            if (keep) { keep[2 * t] = lo; keep[2 * t + 1] = hi; }
            stA(t * 16 + g * 4, lo, hi);
        }
    };
    auto ldfrag = [&](bf8_t (&f)[4]) {
        f[0] = ld8(0 + g * 8); f[1] = ld8(32 + g * 8);
        f[2] = ld8(64 + g * 8); f[3] = ld8(96 + g * 8);
    };
    // second layer over a ws A-operand (K1b/K2b/V1T rows), split acc chain
    auto kmul = [&](const unsigned short* wsKb, const bf8_t (&f)[4]) -> f4_t {
        const unsigned short* ar = wsKb + lr * 128 + g * 8;
        f4_t za = {0.f, 0.f, 0.f, 0.f}, zb = {0.f, 0.f, 0.f, 0.f};
        za = MFMA16(*reinterpret_cast<const bf8_t*>(ar), f[0], za);
        zb = MFMA16(*reinterpret_cast<const bf8_t*>(ar + 32), f[1], zb);
        za = MFMA16(*reinterpret_cast<const bf8_t*>(ar + 64), f[2], za);
        zb = MFMA16(*reinterpret_cast<const bf8_t*>(ar + 96), f[3], zb);
        f4_t k;
        k[0] = za[0] + zb[0]; k[1] = za[1] + zb[1];
        k[2] = za[2] + zb[2]; k[3] = za[3] + zb[3];
        return k;
    };

    // ---- K1 net (through act buf) ----
    actnet(wsK1a, K1a_b, nullptr);
    bf8_t frag[4];
    ldfrag(frag);
    f4_t k1 = kmul(wsK1b, frag);
    // ---- K2 net ----
    actnet(wsK2a, K2a_b, nullptr);
    ldfrag(frag);
    f4_t k2 = kmul(wsK2b, frag);

    // ---- t1 net: buf + reg copy (for the c-step) ----
    unsigned T1[16];
    actnet(wsV1, V1_b, T1);
    bf8_t t1f[4];
    ldfrag(t1f);

    // ---- t2 pass: Z2^T = V2 . t1^T; V partials; s2 -> buf ----
    float vsum = 0.f;
#pragma unroll
    for (int t = 0; t < 8; ++t) {
        f4_t za = {0.f, 0.f, 0.f, 0.f}, zb = {0.f, 0.f, 0.f, 0.f};
        za = MFMA16(ldW(V2s, t, 0), t1f[0], za);
        zb = MFMA16(ldW(V2s, t, 1), t1f[1], zb);
        za = MFMA16(ldW(V2s, t, 2), t1f[2], za);
        zb = MFMA16(ldW(V2s, t, 3), t1f[3], zb);
        f4_t bs = *reinterpret_cast<const f4_t*>(V2_b + t * 16 + g * 4);
        float s0, s1, s2v, s3;
        {
            float t2;
            t2 = fast_tanh(za[0] + zb[0] + bs[0]); vsum = fmaf(t2, t2, vsum); s0 = t2 * (1.f - t2 * t2);
            t2 = fast_tanh(za[1] + zb[1] + bs[1]); vsum = fmaf(t2, t2, vsum); s1 = t2 * (1.f - t2 * t2);
            t2 = fast_tanh(za[2] + zb[2] + bs[2]); vsum = fmaf(t2, t2, vsum); s2v = t2 * (1.f - t2 * t2);
            t2 = fast_tanh(za[3] + zb[3] + bs[3]); vsum = fmaf(t2, t2, vsum); s3 = t2 * (1.f - t2 * t2);
        }
        stA(t * 16 + g * 4, pk2(s0, s1), pk2(s2v, s3));
    }
    bf8_t s2f[4];
    ldfrag(s2f);

    // ---- w^T = V2^T . s2^T ----
    f4_t wacc[8];
#pragma unroll
    for (int t = 0; t < 8; ++t) {
        f4_t za = {0.f, 0.f, 0.f, 0.f}, zb = {0.f, 0.f, 0.f, 0.f};
        za = MFMA16(ldW(V2Ts, t, 0), s2f[0], za);
        zb = MFMA16(ldW(V2Ts, t, 1), s2f[1], zb);
        za = MFMA16(ldW(V2Ts, t, 2), s2f[2], za);
        zb = MFMA16(ldW(V2Ts, t, 3), s2f[3], zb);
        wacc[t][0] = za[0] + zb[0]; wacc[t][1] = za[1] + zb[1];
        wacc[t][2] = za[2] + zb[2]; wacc[t][3] = za[3] + zb[3];
    }

    // ---- c = w * (1 - t1^2) -> buf (T1 is lane-local) ----
#pragma unroll
    for (int t = 0; t < 8; ++t) {
        float t0v = unbf(T1[2 * t]), t1v = unbf_hi(T1[2 * t]);
        float t2v = unbf(T1[2 * t + 1]), t3v = unbf_hi(T1[2 * t + 1]);
        float c0 = wacc[t][0] * (1.f - t0v * t0v);
        float c1 = wacc[t][1] * (1.f - t1v * t1v);
        float c2 = wacc[t][2] * (1.f - t2v * t2v);
        float c3 = wacc[t][3] * (1.f - t3v * t3v);
        stA(t * 16 + g * 4, pk2(c0, c1), pk2(c2, c3));
    }
    bf8_t cf[4];
    ldfrag(cf);

    // ---- gV^T = V1^T . c^T ----
    f4_t gacc = kmul(wsV1T, cf);

    // ---- f^T = A_dyn . x^T ----
    bf8_t afA = {0, 0, 0, 0, 0, 0, 0, 0};
    if (g < 2) afA = *reinterpret_cast<const bf8_t*>(wsA + lr * 16 + g * 8);
    f4_t fz = {0.f, 0.f, 0.f, 0.f};
    f4_t fac = MFMA16(afA, xf, fz);

    // ---- epilogue ----
    f4_t xv = *reinterpret_cast<const f4_t*>(x + bb * 16 + g * 4);
    f4_t xg = *reinterpret_cast<const f4_t*>(x_goal + g * 4);
    f4_t k1b = *reinterpret_cast<const f4_t*>(K1b_b + g * 4);
    f4_t k2b = *reinterpret_cast<const f4_t*>(K2b_b + g * 4);
    f4_t bd0 = *reinterpret_cast<const f4_t*>(B_dyn + g * 8);
    f4_t bd1 = *reinterpret_cast<const f4_t*>(B_dyn + g * 8 + 4);
    float up0 = 0.f, up1 = 0.f, Lf = 0.f;
#pragma unroll
    for (int r = 0; r < 4; ++r) {
        float dx = xv[r] - xg[r];
        up0 = fmaf(k1[r] + k1b[r], dx, up0);
        up1 = fmaf(k2[r] + k2b[r], dx, up1);
        Lf = fmaf(gacc[r], fac[r], Lf);
    }
    float Lg0 = gacc[0] * bd0[0] + gacc[1] * bd0[2] + gacc[2] * bd1[0] + gacc[3] * bd1[2];
    float Lg1 = gacc[0] * bd0[1] + gacc[1] * bd0[3] + gacc[2] * bd1[1] + gacc[3] * bd1[3];
    up0 += __shfl_xor(up0, 16); up0 += __shfl_xor(up0, 32);
    up1 += __shfl_xor(up1, 16); up1 += __shfl_xor(up1, 32);
    Lf += __shfl_xor(Lf, 16); Lf += __shfl_xor(Lf, 32);
    Lg0 += __shfl_xor(Lg0, 16); Lg0 += __shfl_xor(Lg0, 32);
    Lg1 += __shfl_xor(Lg1, 16); Lg1 += __shfl_xor(Lg1, 32);
    vsum += __shfl_xor(vsum, 16); vsum += __shfl_xor(vsum, 32);

    float u0 = u_eq[0] - up0;
    float u1 = u_eq[1] - up1;
    float V = 0.5f * vsum;
    float G = fmaf(Lg0, u0, fmaf(Lg1, u1, V));
    float Vd = 0.5f * (fmaxf(Lf + G, 0.f) + fmaxf(fmaf(1.2f, Lf, G), 0.f));

    if (g == 0) {
        float2 uo; uo.x = u0; uo.y = u1;
        *reinterpret_cast<float2*>(out + 2 * bb) = uo;
    } else if (g == 1) {
        out[2 * B + 1 + bb] = V;
    } else if (g == 2) {
        out[3 * B + 1 + bb] = Vd;
    }
}

extern "C" void kernel_launch(void* const* d_in, const int* in_sizes, int n_in,
                              void* d_out, int out_size, void* d_ws, size_t ws_size,
                              hipStream_t stream) {
    const float* x = (const float*)d_in[0];
    const float* V1_w = (const float*)d_in[1];
    const float* V1_b = (const float*)d_in[2];
    const float* V2_w = (const float*)d_in[3];
    const float* V2_b = (const float*)d_in[4];
    const float* K1a_w = (const float*)d_in[5];
    const float* K1a_b = (const float*)d_in[6];
    const float* K1b_w = (const float*)d_in[7];
    const float* K1b_b = (const float*)d_in[8];
    const float* K2a_w = (const float*)d_in[9];
    const float* K2a_b = (const float*)d_in[10];
    const float* K2b_w = (const float*)d_in[11];
    const float* K2b_b = (const float*)d_in[12];
    const float* A_dyn = (const float*)d_in[13];
    const float* B_dyn = (const float*)d_in[14];
    const float* x_goal = (const float*)d_in[15];
    const float* u_eq = (const float*)d_in[16];
    float* out = (float*)d_out;
    unsigned short* ws = (unsigned short*)d_ws;

    const int B = in_sizes[0] / 16;   // 65536
    const size_t smem = 131072;       // 128 KB
    (void)hipFuncSetAttribute(reinterpret_cast<const void*>(clf_mfma_kernel),
                              hipFuncAttributeMaxDynamicSharedMemorySize, (int)smem);
    prep_weights<<<64, 256, 0, stream>>>(V1_w, V2_w, K1a_w, K1b_w, K2a_w, K2b_w, A_dyn, ws);
    clf_mfma_kernel<<<256, 1024, smem, stream>>>(
        x, V1_b, V2_b, K1a_b, K1b_b, K2a_b, K2b_b,
        B_dyn, x_goal, u_eq, ws, out, B);
}